// Round 11
// baseline (149.375 us; speedup 1.0000x reference)
//
#include <hip/hip_runtime.h>
#include <hip/hip_bf16.h>

#define B_    8
#define CIN   64
#define COUT  64
#define RN_   4
#define H_    128
#define W_    128
#define HW_   (H_ * W_)
#define BN_EPS 1e-5f

typedef short v8s __attribute__((ext_vector_type(8)));
typedef float v4f __attribute__((ext_vector_type(4)));
typedef float v16f __attribute__((ext_vector_type(16)));

__device__ __forceinline__ unsigned short f2bf(float f) {
    unsigned int u = __float_as_uint(f);
    u += 0x7FFFu + ((u >> 16) & 1u);       // round-to-nearest-even
    return (unsigned short)(u >> 16);
}

// ---------------------------------------------------------------------------
// prep: merged transpose kernels (one launch)
//   blocks [0,1024):    x fp32 [b][c][h][w] -> xT bf16 [b][h][w][c]
//   blocks [1024,1152): kernel fp32 -> kT bf16 in 32x32x16 MFMA A-frag order:
//                       tile(b,r,t) = 8 frags (q = mt*4 + kstep) x 64 lanes x
//                       8 ch, lane l holds A[o = mt*32 + (l&31)]
//                                          [c = kstep*16 + (l>>5)*8 + j]
//   block  1152:        mask weights fp32 [r][c][t] -> mwT bf16 (16x16 order,
//                       for the logits pre-pass, unchanged)
// ---------------------------------------------------------------------------
__global__ __launch_bounds__(256) void prep(const float* __restrict__ x,
                                            const float* __restrict__ kr,
                                            const float* __restrict__ mw,
                                            unsigned short* __restrict__ xT,
                                            unsigned short* __restrict__ kT,
                                            unsigned short* __restrict__ mwT) {
    __shared__ float sl[16 * 64 * 9];                 // 36 KB (union of both uses)
    if (blockIdx.x < 1024) {
        const int b = blockIdx.x >> 7, h = blockIdx.x & 127;
        const float* xp = x + (size_t)b * CIN * HW_ + (size_t)h * W_;
        for (int idx = threadIdx.x; idx < CIN * (W_ / 4); idx += 256) {
            const int c = idx >> 5, w4 = (idx & 31) << 2;   // float4 loads (G13)
            const float4 v = *(const float4*)(xp + (size_t)c * HW_ + w4);
            float* s = &sl[c * 129 + w4];                   // 129-pad: conflict-free col reads
            s[0] = v.x; s[1] = v.y; s[2] = v.z; s[3] = v.w;
        }
        __syncthreads();
        unsigned short* op = xT + ((size_t)b * H_ + h) * (W_ * CIN);
        for (int idx = threadIdx.x; idx < (W_ * CIN) / 8; idx += 256) {
            const int w = idx >> 3, c0 = (idx & 7) << 3;
            int4 v;
            v.x = f2bf(sl[(c0 + 0) * 129 + w]) | ((unsigned)f2bf(sl[(c0 + 1) * 129 + w]) << 16);
            v.y = f2bf(sl[(c0 + 2) * 129 + w]) | ((unsigned)f2bf(sl[(c0 + 3) * 129 + w]) << 16);
            v.z = f2bf(sl[(c0 + 4) * 129 + w]) | ((unsigned)f2bf(sl[(c0 + 5) * 129 + w]) << 16);
            v.w = f2bf(sl[(c0 + 6) * 129 + w]) | ((unsigned)f2bf(sl[(c0 + 7) * 129 + w]) << 16);
            *(int4*)(op + (w << 6) + c0) = v;
        }
    } else if (blockIdx.x < 1152) {
        const int bid = blockIdx.x - 1024;
        const int br = bid >> 2, oq = bid & 3;        // br = b*4+r; oq = 16-o chunk
        const float* src = kr + ((size_t)br * 64 + oq * 16) * (64 * 9);
        for (int idx = threadIdx.x; idx < 2304; idx += 256)
            *(float4*)&sl[idx << 2] = *(const float4*)&src[idx << 2];
        __syncthreads();
        unsigned short* dst = kT + (size_t)br * (9 * 4096);
        for (int idx = threadIdx.x; idx < 1152; idx += 256) {
            const int t = idx >> 7, rem = idx & 127, o16 = rem >> 3, c8 = (rem & 7) << 3;
            unsigned short s[8];
            #pragma unroll
            for (int j = 0; j < 8; j++)
                s[j] = f2bf(sl[(o16 * 64 + c8 + j) * 9 + t]);
            int4 v;
            v.x = s[0] | ((unsigned)s[1] << 16);
            v.y = s[2] | ((unsigned)s[3] << 16);
            v.z = s[4] | ((unsigned)s[5] << 16);
            v.w = s[6] | ((unsigned)s[7] << 16);
            // 32x32x16 fragment coords: o = oq*16+o16 -> mt=oq>>1, l&31=(oq&1)*16+o16
            //                           c = c8+j -> kstep=c8>>4, khalf=(c8>>3)&1
            const int kstep = c8 >> 4;
            const int khalf = (c8 >> 3) & 1;
            const int l = khalf * 32 + (oq & 1) * 16 + o16;
            const int q = (oq >> 1) * 4 + kstep;
            *(int4*)(dst + (size_t)t * 4096 + q * 512 + l * 8) = v;
        }
    } else {
        // mwT[tile=tap*2+ks][lane][8]: lane=(g<<4)|i, row i holds region i&3
        for (int idx = threadIdx.x; idx < 9 * 2 * 64 * 8; idx += 256) {
            const int tile = idx >> 9;                // tap*2+ks
            const int tap = tile >> 1, ks = tile & 1;
            const int lane = (idx >> 3) & 63, j = idx & 7;
            const int g = lane >> 4, r = lane & 3;    // region = i&3
            const int c = ks * 32 + g * 8 + j;
            mwT[idx] = f2bf(mw[(r * 64 + c) * 9 + tap]);
        }
    }
}

// ---------------------------------------------------------------------------
// fused: dynamic grouped conv + mask conv/softmax + region sum + BN + ReLU.
// Round 11 = r5 structure (best: 45.1us, barrier-free drift kept — r10
// falsified the phaser) with the K-loop ported to 32x32x16 MFMA:
//   - 16 MFMA/tap @ 8.07cyc = 129 cyc vs 32 @ 4.85 = 155 (-17% pipe time,
//     -50% issue slots); same A bytes/MFMA (256B), same LDS traffic.
//   - 32x32 C/D layout (col = lane&31) -> epilogue stores are two full
//     128B lines per instruction (r5 wrote 64B half-lines: WRITE_SIZE
//     34.8MB vs 18.9MB output — partial-line amplification).
//   - per-lane mask packs pre-selected (no dynamic reg-array indexing).
// ---------------------------------------------------------------------------
#define XS_W     66                      // 64 + 2 halo columns
#define XS_ROWS  6                       // 4 output rows + 2 halo rows
#define XS_ELEMS (XS_ROWS * XS_W * 64)   // 25344 shorts = 50.7 KB, swizzled

__global__ __launch_bounds__(256, 2) void main_conv(
        const unsigned short* __restrict__ xT,
        const unsigned short* __restrict__ kT,
        const unsigned short* __restrict__ mwT,
        const float* __restrict__ mb,
        const float* __restrict__ bn_gamma, const float* __restrict__ bn_beta,
        const float* __restrict__ bn_mean,  const float* __restrict__ bn_var,
        float* __restrict__ outp, float* __restrict__ masks_g) {
    __shared__ __align__(16) unsigned short xs[XS_ELEMS];
    __shared__ float scale_s[COUT];
    __shared__ float shift_s[COUT];

    const int tid = threadIdx.x;
    const int b  = blockIdx.z;
    const int w0 = blockIdx.y << 6;           // 0 or 64
    const int h0 = blockIdx.x << 2;           // 0..124
    const int lane = tid & 63, wv = tid >> 6; // wave wv owns output row h0+wv
    const int i = lane & 15, g = lane >> 4;
    const int l31 = lane & 31, kh = lane >> 5;    // 32x32 operand coords
    const int h_out = h0 + wv;

    // ---- stage x halo tile, XOR-swizzled: slot' = slot ^ (rw&7) ----
    const unsigned short* xb = xT + (size_t)b * (HW_ * CIN);
    #pragma unroll
    for (int row = 0; row < XS_ROWS; row++) {
        const int h_in = h0 - 1 + row;
        const bool hok = (h_in >= 0) && (h_in < H_);
        for (int idx = tid; idx < XS_W * 8; idx += 256) {
            const int w = idx >> 3, c8 = (idx & 7) << 3;
            const int w_in = w0 - 1 + w;
            int4 v = make_int4(0, 0, 0, 0);
            if (hok && (w_in >= 0) && (w_in < W_))
                v = *(const int4*)(xb + ((h_in * W_ + w_in) << 6) + c8);
            const int rw = row * XS_W + w;
            *(int4*)(&xs[(rw << 6) + (((c8 >> 3) ^ (rw & 7)) << 3)]) = v;
        }
    }
    if (tid < COUT) {
        const float sc = bn_gamma[tid] * rsqrtf(bn_var[tid] + BN_EPS);
        scale_s[tid] = sc;
        shift_s[tid] = bn_beta[tid] - bn_mean[tid] * sc;
    }
    const float mb0 = mb[0], mb1 = mb[1], mb2 = mb[2], mb3 = mb[3];

    __syncthreads();                          // xs ready; K-loop stays barrier-free

    // ---- logits pre-pass: 9 taps, 16x16 MFMA, A = mwT global (unchanged) ----
    v4f lg_acc[4];
    #pragma unroll
    for (int fn = 0; fn < 4; fn++) lg_acc[fn] = (v4f){0.f, 0.f, 0.f, 0.f};
    for (int tap = 0; tap < 9; tap++) {
        const int rwb = (wv + tap / 3) * XS_W + i + tap % 3;
        const int base = (rwb << 6) + ((g ^ (rwb & 7)) << 3);
        #pragma unroll
        for (int ks = 0; ks < 2; ks++) {
            const v8s am = *(const v8s*)(mwT + (((tap * 2 + ks) << 9) + (lane << 3)));
            #pragma unroll
            for (int fn = 0; fn < 4; fn++) {
                const v8s bv = *(const v8s*)(&xs[(base + (fn << 10)) ^ (ks << 5)]);
                lg_acc[fn] = __builtin_amdgcn_mfma_f32_16x16x32_bf16(am, bv, lg_acc[fn], 0, 0, 0);
            }
        }
    }
    unsigned mk0[4], mk1[4];                  // bf16-packed clamped masks (r0|r1),(r2|r3)
    #pragma unroll
    for (int fn = 0; fn < 4; fn++) {
        const float l0 = lg_acc[fn][0] + mb0, l1 = lg_acc[fn][1] + mb1;
        const float l2 = lg_acc[fn][2] + mb2, l3 = lg_acc[fn][3] + mb3;
        const float mx = fmaxf(fmaxf(l0, l1), fmaxf(l2, l3));
        const float e0 = __expf(l0 - mx), e1 = __expf(l1 - mx);
        const float e2 = __expf(l2 - mx), e3 = __expf(l3 - mx);
        const float inv = 1.f / (e0 + e1 + e2 + e3);
        const float m0 = e0 * inv, m1 = e1 * inv, m2 = e2 * inv, m3 = e3 * inv;
        if (g == 0) {                         // lanes 0..15 hold valid rows 0..3
            float* mp = masks_g + ((size_t)b * RN_ * H_ + h_out) * W_ + w0 + fn * 16 + i;
            mp[0] = m0; mp[HW_] = m1; mp[2 * HW_] = m2; mp[3 * HW_] = m3;
        }
        mk0[fn] = f2bf(fmaxf(m0, 1e-12f)) | ((unsigned)f2bf(fmaxf(m1, 1e-12f)) << 16);
        mk1[fn] = f2bf(fmaxf(m2, 1e-12f)) | ((unsigned)f2bf(fmaxf(m3, 1e-12f)) << 16);
    }
    // broadcast from g==0 lane of col i, then select this lane's column pack
    // for each 32-col tile tn: fn' = tn*2 + ((lane&31)>>4), idx = lane&15.
    #pragma unroll
    for (int fn = 0; fn < 4; fn++) {
        mk0[fn] = __shfl(mk0[fn], i);
        mk1[fn] = __shfl(mk1[fn], i);
    }
    const int hsel = (l31 >> 4) & 1;          // which 16-col half of the 32-tile
    unsigned pk01[2], pk23[2];                // [tn] static-indexed (rule #20)
    pk01[0] = hsel ? mk0[1] : mk0[0];  pk23[0] = hsel ? mk1[1] : mk1[0];
    pk01[1] = hsel ? mk0[3] : mk0[2];  pk23[1] = hsel ? mk1[3] : mk1[2];
    auto mvalT = [&](int tn, int rr) -> float {   // tn compile-time at all uses
        const unsigned pk = (rr & 2) ? pk23[tn] : pk01[tn];
        return (rr & 1) ? __uint_as_float(pk & 0xffff0000u)
                        : __uint_as_float(pk << 16);
    };

    // ---- main loop: A dbuf from global (frag q = mt*4+kstep), B dbuf from
    //      LDS 1 tap ahead; 16x v_mfma_f32_32x32x16_bf16 per tap ----
    const unsigned short* kb = kT + (size_t)b * (36 * 4096) + (lane << 3);
    v16f o_acc[2][2];
    #pragma unroll
    for (int mt = 0; mt < 2; mt++)
        #pragma unroll
        for (int tn = 0; tn < 2; tn++)
            #pragma unroll
            for (int c = 0; c < 16; c++)
                o_acc[mt][tn][c] = 0.f;

    v8s aA[8], aB[8], b0[8], b1[8];
    auto lda = [&](v8s (&dst)[8], int t) {
        const unsigned short* kp = kb + ((size_t)t << 12);
        #pragma unroll
        for (int q = 0; q < 8; q++) dst[q] = *(const v8s*)(kp + (q << 9));
    };
    // B-frag for (tn,kstep): lane l reads x[row = wv + t/3][col = tn*32+l31+t%3]
    // channels c = kstep*16 + kh*8 .. +7  (swizzled group kgrp = kstep*2+kh)
    auto ldb = [&](v8s (&dst)[8], int t) {
        const int rbase = (wv + t / 3) * XS_W + l31 + t % 3;
        #pragma unroll
        for (int tn = 0; tn < 2; tn++) {
            const int rwb = rbase + tn * 32;
            const int rowoff = rwb << 6;
            const int r7 = rwb & 7;
            #pragma unroll
            for (int kstep = 0; kstep < 4; kstep++) {
                const int kgrp = kstep * 2 + kh;
                dst[tn * 4 + kstep] = *(const v8s*)(&xs[rowoff + ((kgrp ^ r7) << 3)]);
            }
        }
    };

    lda(aA, 0); lda(aB, 1);
    ldb(b0, 0);

    int tap = 0, r = 0;
    auto step = [&](const v8s (&ac)[8], const v8s (&bc)[8], v8s (&bn)[8]) {
        const int ntap = (tap == 8) ? 0 : tap + 1;
        ldb(bn, ntap);                        // prefetch next tap's B-frags
        __builtin_amdgcn_s_setprio(1);
        #pragma unroll
        for (int kstep = 0; kstep < 4; kstep++)
            #pragma unroll
            for (int mt = 0; mt < 2; mt++)
                #pragma unroll
                for (int tn = 0; tn < 2; tn++)
                    o_acc[mt][tn] = __builtin_amdgcn_mfma_f32_32x32x16_bf16(
                        ac[mt * 4 + kstep], bc[tn * 4 + kstep], o_acc[mt][tn], 0, 0, 0);
        __builtin_amdgcn_s_setprio(0);
        if (++tap == 9) {                     // region done: Horner fold
            tap = 0;
            if (r < 3) {
                #pragma unroll
                for (int tn = 0; tn < 2; tn++) {
                    const float ratio = mvalT(tn, r) / mvalT(tn, r + 1);
                    #pragma unroll
                    for (int mt = 0; mt < 2; mt++)
                        #pragma unroll
                        for (int c = 0; c < 16; c++)
                            o_acc[mt][tn][c] *= ratio;
                }
            }
            r++;
        }
    };

    for (int rt = 0; rt < 36; rt += 2) {
        step(aA, b0, b1);
        if (rt + 2 < 36) lda(aA, rt + 2);
        step(aB, b1, b0);
        if (rt + 3 < 36) lda(aB, rt + 3);
    }

    // ---- epilogue: *m3 (Horner final), BN + ReLU + store (full 128B lines:
    //      per (mt,reg,tn) instruction lanes 0..31 / 32..63 each cover 128B) ----
    #pragma unroll
    for (int mt = 0; mt < 2; mt++) {
        #pragma unroll
        for (int reg = 0; reg < 16; reg++) {
            const int row = (reg & 3) + 8 * (reg >> 2) + 4 * kh;  // C/D row map
            const int oc = mt * 32 + row;
            const float sc = scale_s[oc], sh = shift_s[oc];
            #pragma unroll
            for (int tn = 0; tn < 2; tn++) {
                const float v = o_acc[mt][tn][reg] * mvalT(tn, 3) * sc + sh;
                outp[(((size_t)b * COUT + oc) * H_ + h_out) * W_ + w0 + tn * 32 + l31]
                    = fmaxf(v, 0.f);
            }
        }
    }
}

// ---------------------------------------------------------------------------
extern "C" void kernel_launch(void* const* d_in, const int* in_sizes, int n_in,
                              void* d_out, int out_size, void* d_ws, size_t ws_size,
                              hipStream_t stream) {
    const float* x     = (const float*)d_in[0];
    const float* kr    = (const float*)d_in[1];
    const float* mw    = (const float*)d_in[2];
    const float* mb    = (const float*)d_in[3];
    const float* gamma = (const float*)d_in[4];
    const float* beta  = (const float*)d_in[5];
    const float* mean  = (const float*)d_in[6];
    const float* var   = (const float*)d_in[7];

    float* outp  = (float*)d_out;
    float* masks = outp + (size_t)B_ * COUT * HW_;          // output #2 region

    unsigned short* xT  = (unsigned short*)d_ws;            // 16 MiB
    unsigned short* kT  = xT + (size_t)B_ * HW_ * CIN;      // +2.25 MiB
    unsigned short* mwT = kT + (size_t)B_ * RN_ * 9 * 4096; // +18 KiB

    hipLaunchKernelGGL(prep, dim3(1153), dim3(256), 0, stream, x, kr, mw, xT, kT, mwT);
    hipLaunchKernelGGL(main_conv, dim3(H_ / 4, 2, B_), dim3(256), 0, stream,
                       xT, kT, mwT, mb, gamma, beta, mean, var, outp, masks);
}